// Round 15
// baseline (232.003 us; speedup 1.0000x reference)
//
#include <hip/hip_runtime.h>
#include <hip/hip_bf16.h>

#define N_NODES 20000
#define N_EDGES 320000
#define F_IN 256
#define HID 64
#define HEADS 8
#define NCLS 64
#define D1 (HEADS * HID)   // 512
#define SCAN_BLOCKS ((N_NODES + 255) / 256)   // 79

typedef __attribute__((ext_vector_type(8))) short short8;
typedef __attribute__((ext_vector_type(4))) float floatx4;
typedef __attribute__((ext_vector_type(2))) float v2f;

__device__ __forceinline__ ushort f2bf(float f) {
    unsigned u = __float_as_uint(f);
    unsigned r = (u + 0x7fffu + ((u >> 16) & 1u)) >> 16;
    return (ushort)r;
}
__device__ __forceinline__ v2f unpack2(unsigned u) {
    v2f r;
    r.x = __uint_as_float(u << 16);
    r.y = __uint_as_float(u & 0xffff0000u);
    return r;
}
template <int CTRL>
__device__ __forceinline__ float dppadd(float x) {
    int y = __builtin_amdgcn_update_dpp(0, __float_as_int(x), CTRL, 0xF, 0xF, true);
    return x + __int_as_float(y);
}
__device__ __forceinline__ float rowsum16(float x) {
    x = dppadd<0xB1>(x);     // quad_perm [1,0,3,2]
    x = dppadd<0x4E>(x);     // quad_perm [2,3,0,1]
    x = dppadd<0x124>(x);    // row_ror:4
    x = dppadd<0x128>(x);    // row_ror:8
    return x;
}
// async global->LDS 16B per lane (wave-level): LDS dest = uniform base + lane*16
__device__ __forceinline__ void async_copy16(ushort* lds, const ushort* g) {
    __builtin_amdgcn_global_load_lds(
        (const __attribute__((address_space(1))) void*)g,
        (__attribute__((address_space(3))) void*)lds, 16, 0, 0);
}

// ---------- fused preprocess: x->bf16, 4 weight transposes (coalesced reads), histogram ----------
#define PB_HIST 1250
#define PB_CONV 5000
#define PB_T1   512
#define PB_T2   128
#define PB_TOTAL (PB_HIST + PB_CONV + 2 * PB_T1 + 2 * PB_T2)  // 7530
__global__ __launch_bounds__(256) void preprocess(
    const float* __restrict__ x, ushort* __restrict__ xbf,
    const float* __restrict__ Wl1, const float* __restrict__ Wr1,
    const float* __restrict__ Wl2, const float* __restrict__ Wr2,
    ushort* __restrict__ wt1, ushort* __restrict__ wt2,
    const int* __restrict__ dst, int* __restrict__ cnt) {
    int b = blockIdx.x, t = threadIdx.x;
    if (b < PB_HIST) {
        int i = b * 256 + t;
        if (i < N_EDGES) atomicAdd(&cnt[dst[i]], 1);
    } else if (b < PB_HIST + PB_CONV) {
        int i = (b - PB_HIST) * 256 + t;   // float4 index
        if (i < N_NODES * F_IN / 4) {
            float4 v = ((const float4*)x)[i];
            ushort4 o;
            o.x = f2bf(v.x); o.y = f2bf(v.y); o.z = f2bf(v.z); o.w = f2bf(v.w);
            ((ushort4*)xbf)[i] = o;
        }
    } else if (b < PB_HIST + PB_CONV + 2 * PB_T1) {
        int lb = b - PB_HIST - PB_CONV;
        const float* W = (lb < PB_T1) ? Wl1 : Wr1;
        ushort* Wt = wt1 + ((lb < PB_T1) ? 0 : D1 * F_IN);
        int i = (lb % PB_T1) * 256 + t;    // linear over W[k][n], k<256, n<512: coalesced read
        if (i < D1 * F_IN) {
            Wt[(i & 511) * 256 + (i >> 9)] = f2bf(W[i]);
        }
    } else {
        int lb = b - PB_HIST - PB_CONV - 2 * PB_T1;
        const float* W = (lb < PB_T2) ? Wl2 : Wr2;
        ushort* Wt = wt2 + ((lb < PB_T2) ? 0 : NCLS * D1);
        int i = (lb % PB_T2) * 256 + t;    // linear over W[k][n], k<512, n<64: coalesced read
        if (i < NCLS * D1) {
            Wt[(i & 63) * 512 + (i >> 6)] = f2bf(W[i]);
        }
    }
}

// ---------- CSR scan (parallel 2-kernel) ----------
__global__ __launch_bounds__(256) void scan_local(const int* __restrict__ cnt,
                                                  int* __restrict__ pscan,
                                                  int* __restrict__ bsum, int n) {
    int tid = threadIdx.x;
    int i = blockIdx.x * 256 + tid;
    int lane = tid & 63, wave = tid >> 6;
    int v = (i < n) ? cnt[i] : 0;
    int x = v;
    #pragma unroll
    for (int d = 1; d < 64; d <<= 1) {
        int y = __shfl_up(x, d);
        if (lane >= d) x += y;
    }
    __shared__ int wsum[4];
    if (lane == 63) wsum[wave] = x;
    __syncthreads();
    int woff = 0;
    for (int w2 = 0; w2 < wave; w2++) woff += wsum[w2];
    int incl = x + woff;
    if (i < n) pscan[i] = incl;
    if (tid == 255) bsum[blockIdx.x] = incl;
}

__global__ __launch_bounds__(256) void scan_finalize(const int* __restrict__ cnt,
                                                     const int* __restrict__ pscan,
                                                     const int* __restrict__ bsum,
                                                     int* __restrict__ row_ptr,
                                                     int* __restrict__ cursor, int n) {
    int t = threadIdx.x;
    int lane = t & 63, wave = t >> 6;
    int v = (t < SCAN_BLOCKS && t < blockIdx.x) ? bsum[t] : 0;
    #pragma unroll
    for (int mask = 1; mask < 64; mask <<= 1) v += __shfl_xor(v, mask);
    __shared__ int ws[4];
    __shared__ int soff;
    if (lane == 0) ws[wave] = v;
    __syncthreads();
    if (t == 0) soff = ws[0] + ws[1] + ws[2] + ws[3];
    __syncthreads();
    int i = blockIdx.x * 256 + t;
    if (i < n) {
        int incl = pscan[i] + soff;
        row_ptr[i + 1] = incl;
        cursor[i] = incl - cnt[i];
    }
    if (i == 0) row_ptr[0] = 0;
}

// ---------- fused gemm1 (128x128 bf16 MFMA, BK=64, K-outer LDS) + edge scatter ----------
// LDS layout [kc][row][8]: fragment reads are 16 sequential 16B chunks per
// 16-lane group -> conflict-free; BK=64 halves barrier drains (4 iters).
#define G1_NT 8
#define G1_MT ((N_NODES + 127) / 128) // 157
#define G1_BLOCKS (G1_NT * G1_MT)     // 1256
#define SC_BLOCKS (N_EDGES / 256)     // 1250
__global__ __launch_bounds__(256) void gemm1_scatter(
    const ushort* __restrict__ A, const ushort* __restrict__ Bt,
    ushort* __restrict__ C,
    const int* __restrict__ src, const int* __restrict__ dst,
    int* __restrict__ cursor, int* __restrict__ csr_src) {
    if (blockIdx.x >= G1_BLOCKS) {
        int i = (blockIdx.x - G1_BLOCKS) * 256 + threadIdx.x;
        if (i < N_EDGES) {
            int d = dst[i];
            int pos = atomicAdd(&cursor[d], 1);
            csr_src[pos] = src[i];
        }
        return;
    }
    const int M = N_NODES, N = 2 * D1, K = F_IN;
    __shared__ ushort As[8 * 128 * 8];   // 16 KB: [kc][r][8]
    __shared__ ushort Bs[8 * 128 * 8];   // 16 KB
    int tid = threadIdx.x;
    int rowBase = (blockIdx.x >> 3) * 128, colBase = (blockIdx.x & 7) * 128;
    int wave = tid >> 6, lane = tid & 63;
    int quad = lane >> 4, m16 = lane & 15;
    int rh = wave >> 1, chf = wave & 1;
    floatx4 acc[4][4];
    #pragma unroll
    for (int i = 0; i < 4; i++)
        #pragma unroll
        for (int j = 0; j < 4; j++) acc[i][j] = (floatx4){0.f, 0.f, 0.f, 0.f};

    for (int k0 = 0; k0 < K; k0 += 64) {
        #pragma unroll
        for (int i = 0; i < 4; i++) {
            int idx = i * 256 + tid;          // 0..1023
            int kc = idx >> 7, r = idx & 127; // chunk-major
            int grow = min(rowBase + r, M - 1);
            async_copy16(&As[idx * 8], A + (size_t)grow * K + k0 + kc * 8);
            async_copy16(&Bs[idx * 8], Bt + (size_t)(colBase + r) * K + k0 + kc * 8);
        }
        __syncthreads();
        #pragma unroll
        for (int kk = 0; kk < 2; kk++) {
            short8 af[4], bfr[4];
            #pragma unroll
            for (int i = 0; i < 4; i++)
                af[i] = *(short8*)&As[((kk * 4 + quad) * 128 + rh * 64 + i * 16 + m16) * 8];
            #pragma unroll
            for (int j = 0; j < 4; j++)
                bfr[j] = *(short8*)&Bs[((kk * 4 + quad) * 128 + chf * 64 + j * 16 + m16) * 8];
            #pragma unroll
            for (int i = 0; i < 4; i++)
                #pragma unroll
                for (int j = 0; j < 4; j++)
                    acc[i][j] = __builtin_amdgcn_mfma_f32_16x16x32_bf16(af[i], bfr[j], acc[i][j], 0, 0, 0);
        }
        __syncthreads();
    }
    #pragma unroll
    for (int i = 0; i < 4; i++)
        #pragma unroll
        for (int j = 0; j < 4; j++)
            #pragma unroll
            for (int r = 0; r < 4; r++) {
                int row = rowBase + rh * 64 + i * 16 + quad * 4 + r;
                if (row < M) C[(size_t)row * N + colBase + chf * 64 + j * 16 + m16] = f2bf(acc[i][j][r]);
            }
}

// ---------- gemm2: 32x128 tile, BK=64, K-outer LDS (625 blocks) ----------
__global__ __launch_bounds__(256) void gemm2_32x128(
    const ushort* __restrict__ A, const ushort* __restrict__ Bt,
    ushort* __restrict__ C) {
    const int K = D1;            // 512
    __shared__ ushort As[8 * 32 * 8];    // 4 KB: [kc][r][8]
    __shared__ ushort Bs[8 * 128 * 8];   // 16 KB
    int tid = threadIdx.x;
    int rowBase = blockIdx.x * 32;
    int wave = tid >> 6, lane = tid & 63;
    int quad = lane >> 4, m16 = lane & 15;
    floatx4 acc[2][2];
    #pragma unroll
    for (int i = 0; i < 2; i++)
        #pragma unroll
        for (int j = 0; j < 2; j++) acc[i][j] = (floatx4){0.f, 0.f, 0.f, 0.f};

    for (int k0 = 0; k0 < K; k0 += 64) {
        {                                           // A tile: 256 chunks, 1/thread
            int kc = tid >> 5, r = tid & 31;
            async_copy16(&As[tid * 8], A + (size_t)(rowBase + r) * K + k0 + kc * 8);
        }
        #pragma unroll
        for (int i = 0; i < 4; i++) {               // B tile: 1024 chunks, 4/thread
            int idx = i * 256 + tid;
            int kc = idx >> 7, r = idx & 127;
            async_copy16(&Bs[idx * 8], Bt + (size_t)r * K + k0 + kc * 8);
        }
        __syncthreads();
        #pragma unroll
        for (int kk = 0; kk < 2; kk++) {
            short8 af[2], bfr[2];
            #pragma unroll
            for (int i = 0; i < 2; i++)
                af[i] = *(short8*)&As[((kk * 4 + quad) * 32 + i * 16 + m16) * 8];
            #pragma unroll
            for (int j = 0; j < 2; j++)
                bfr[j] = *(short8*)&Bs[((kk * 4 + quad) * 128 + wave * 32 + j * 16 + m16) * 8];
            #pragma unroll
            for (int i = 0; i < 2; i++)
                #pragma unroll
                for (int j = 0; j < 2; j++)
                    acc[i][j] = __builtin_amdgcn_mfma_f32_16x16x32_bf16(af[i], bfr[j], acc[i][j], 0, 0, 0);
        }
        __syncthreads();
    }
    #pragma unroll
    for (int i = 0; i < 2; i++)
        #pragma unroll
        for (int j = 0; j < 2; j++)
            #pragma unroll
            for (int r = 0; r < 4; r++) {
                int row = rowBase + i * 16 + quad * 4 + r;
                C[(size_t)row * 128 + wave * 32 + j * 16 + m16] = f2bf(acc[i][j][r]);
            }
}

// ---------- layer-1 fused attention: R12-measured layout (54.8 us) ----------
// 128 thr/block = 2 waves, ONE node; thread t owns channels 4t..4t+3
// (16-lane head groups -> rowsum16 DPP); depth-4 named prefetch; exp2 prescale.
#define L1PROC(cu, valid)                                                     \
    {                                                                         \
        v2f _c01 = unpack2((cu).x), _c23 = unpack2((cu).y);                   \
        v2f _v01 = _c01 + xr01, _v23 = _c23 + xr23;                           \
        v2f _sp = a6_01 * _v01 + a4_01 * __builtin_elementwise_abs(_v01)      \
                + a6_23 * _v23 + a4_23 * __builtin_elementwise_abs(_v23);     \
        float _sc = _sp.x + _sp.y;                                            \
        _sc = rowsum16(_sc);                                                  \
        float _e = (valid) ? exp2f(_sc) : 0.f;                                \
        den += _e;                                                            \
        v2f _ev = {_e, _e};                                                   \
        ac01 = ac01 + _ev * _c01; ac23 = ac23 + _ev * _c23;                   \
    }

__global__ __launch_bounds__(128) void attn_l1_fused(
    const ushort* __restrict__ xlr, const float* __restrict__ att,
    const float* __restrict__ b1,
    const int* __restrict__ row_ptr, const int* __restrict__ csr_src,
    ushort* __restrict__ h1out) {
    int d = blockIdx.x, t = threadIdx.x;
    int start = row_ptr[d], deg = row_ptr[d + 1] - start;

    uint2 xru = *(const uint2*)(xlr + (size_t)d * 1024 + 512 + 4 * t);
    v2f xr01 = unpack2(xru.x), xr23 = unpack2(xru.y);
    const float C6 = 0.6f * 1.44269504f, C4 = 0.4f * 1.44269504f;
    float4 atv = *(const float4*)(att + 4 * t);
    v2f a6_01 = {C6 * atv.x, C6 * atv.y}, a4_01 = {C4 * atv.x, C4 * atv.y};
    v2f a6_23 = {C6 * atv.z, C6 * atv.w}, a4_23 = {C4 * atv.z, C4 * atv.w};

    float den = 0.f;
    v2f ac01 = {0.f, 0.f}, ac23 = {0.f, 0.f};

    if (deg > 0) {
        const int* cs = csr_src + start;
        uint2 q0 = *(const uint2*)(xlr + (size_t)cs[0] * 1024 + 4 * t);
        uint2 q1 = *(const uint2*)(xlr + (size_t)cs[min(1, deg - 1)] * 1024 + 4 * t);
        uint2 q2 = *(const uint2*)(xlr + (size_t)cs[min(2, deg - 1)] * 1024 + 4 * t);
        uint2 q3 = *(const uint2*)(xlr + (size_t)cs[min(3, deg - 1)] * 1024 + 4 * t);
        for (int i0 = 0; i0 < deg; i0 += 4) {
            uint2 e0 = q0, e1 = q1, e2 = q2, e3 = q3;
            if (i0 + 4 < deg) q0 = *(const uint2*)(xlr + (size_t)cs[i0 + 4] * 1024 + 4 * t);
            if (i0 + 5 < deg) q1 = *(const uint2*)(xlr + (size_t)cs[i0 + 5] * 1024 + 4 * t);
            if (i0 + 6 < deg) q2 = *(const uint2*)(xlr + (size_t)cs[i0 + 6] * 1024 + 4 * t);
            if (i0 + 7 < deg) q3 = *(const uint2*)(xlr + (size_t)cs[i0 + 7] * 1024 + 4 * t);
            L1PROC(e0, true)
            L1PROC(e1, i0 + 1 < deg)
            L1PROC(e2, i0 + 2 < deg)
            L1PROC(e3, i0 + 3 < deg)
        }
    }
    float inv = 1.f / (den + 1e-16f);
    float4 bv = *(const float4*)(b1 + 4 * t);
    float o0 = ac01.x * inv + bv.x;
    float o1 = ac01.y * inv + bv.y;
    float o2 = ac23.x * inv + bv.z;
    float o3 = ac23.y * inv + bv.w;
    o0 = o0 > 0.f ? o0 : (__expf(o0) - 1.f);   // ELU
    o1 = o1 > 0.f ? o1 : (__expf(o1) - 1.f);
    o2 = o2 > 0.f ? o2 : (__expf(o2) - 1.f);
    o3 = o3 > 0.f ? o3 : (__expf(o3) - 1.f);
    ushort4 hv;
    hv.x = f2bf(o0); hv.y = f2bf(o1); hv.z = f2bf(o2); hv.w = f2bf(o3);
    *(ushort4*)(h1out + (size_t)d * D1 + 4 * t) = hv;
}

// ---------- layer-2 fused attention: 16-lane groups, 4 edges/wave/step ----------
#define L2PROC(cu, valid)                                                     \
    {                                                                         \
        v2f _c01 = unpack2((cu).x), _c23 = unpack2((cu).y);                   \
        v2f _v01 = _c01 + yr01, _v23 = _c23 + yr23;                           \
        v2f _sp = at6_01 * _v01 + at4_01 * __builtin_elementwise_abs(_v01)    \
                + at6_23 * _v23 + at4_23 * __builtin_elementwise_abs(_v23);   \
        float _sc = _sp.x + _sp.y;                                            \
        _sc = rowsum16(_sc);                                                  \
        float _e = (valid) ? exp2f(_sc) : 0.f;                                \
        den += _e;                                                            \
        v2f _ev = {_e, _e};                                                   \
        ac01 = ac01 + _ev * _c01; ac23 = ac23 + _ev * _c23;                   \
    }

__device__ __forceinline__ float xgroup_sum(float x) {
    float t = __int_as_float(__builtin_amdgcn_ds_swizzle(__float_as_int(x), 0x401F));
    x += t;
    x += __shfl_xor(x, 32);
    return x;
}

__global__ __launch_bounds__(256) void attn_l2_fused(
    const ushort* __restrict__ ylr, const float* __restrict__ att2,
    const float* __restrict__ b2,
    const int* __restrict__ row_ptr, const int* __restrict__ csr_src,
    float* __restrict__ out) {
    int wave = threadIdx.x >> 6, lane = threadIdx.x & 63;
    int d = blockIdx.x * 4 + wave;
    int grp = lane >> 4, l15 = lane & 15;
    int start = row_ptr[d], deg = row_ptr[d + 1] - start;

    uint2 yru = *(const uint2*)(ylr + (size_t)d * 128 + 64 + 4 * l15);
    v2f yr01 = unpack2(yru.x), yr23 = unpack2(yru.y);
    float4 a2 = *(const float4*)(att2 + 4 * l15);
    const float C6 = 0.6f * 1.44269504f, C4 = 0.4f * 1.44269504f;
    v2f at6_01 = {C6 * a2.x, C6 * a2.y}, at4_01 = {C4 * a2.x, C4 * a2.y};
    v2f at6_23 = {C6 * a2.z, C6 * a2.w}, at4_23 = {C4 * a2.z, C4 * a2.w};

    float den = 0.f;
    v2f ac01 = {0.f, 0.f}, ac23 = {0.f, 0.f};

    if (deg > 0) {
        int S = (deg + 3) >> 2;                 // steps of 4 edges
        const int* cs = csr_src + start;
        uint2 q0 = *(const uint2*)(ylr + (size_t)cs[min(grp, deg - 1)] * 128 + 4 * l15);
        uint2 q1 = *(const uint2*)(ylr + (size_t)cs[min(min(1, S - 1) * 4 + grp, deg - 1)] * 128 + 4 * l15);
        for (int i = 0; i < S; i++) {
            uint2 cu = q0;
            q0 = q1;
            if (i + 2 < S) {
                int p = min((i + 2) * 4 + grp, deg - 1);
                q1 = *(const uint2*)(ylr + (size_t)cs[p] * 128 + 4 * l15);
            }
            L2PROC(cu, 4 * i + grp < deg)
        }
        den = xgroup_sum(den);
        ac01.x = xgroup_sum(ac01.x);
        ac01.y = xgroup_sum(ac01.y);
        ac23.x = xgroup_sum(ac23.x);
        ac23.y = xgroup_sum(ac23.y);
    }
    if (grp == 0) {
        float inv = 1.f / (den + 1e-16f);
        float4 bv = *(const float4*)(b2 + 4 * l15);
        float4 o;
        o.x = ac01.x * inv + bv.x;
        o.y = ac01.y * inv + bv.y;
        o.z = ac23.x * inv + bv.z;
        o.w = ac23.y * inv + bv.w;
        *(float4*)(out + (size_t)d * NCLS + 4 * l15) = o;
    }
}

extern "C" void kernel_launch(void* const* d_in, const int* in_sizes, int n_in,
                              void* d_out, int out_size, void* d_ws, size_t ws_size,
                              hipStream_t stream) {
    const float* x    = (const float*)d_in[0];
    const int*   edge = (const int*)d_in[1];
    const float* Wl1  = (const float*)d_in[2];
    const float* Wr1  = (const float*)d_in[3];
    const float* att1 = (const float*)d_in[4];
    const float* b1   = (const float*)d_in[5];
    const float* Wl2  = (const float*)d_in[6];
    const float* Wr2  = (const float*)d_in[7];
    const float* att2 = (const float*)d_in[8];
    const float* b2   = (const float*)d_in[9];
    float* out = (float*)d_out;

    const int* srcv = edge;
    const int* dstv = edge + N_EDGES;

    ushort* xbf  = (ushort*)d_ws;                        // N*256
    ushort* wt1  = xbf + (size_t)N_NODES * F_IN;         // 1024*256 (Wl1^T || Wr1^T)
    ushort* wt2  = wt1 + 2 * D1 * F_IN;                  // 128*512  (Wl2^T || Wr2^T)
    ushort* xlr  = wt2 + 2 * NCLS * D1;                  // N*1024 bf16
    ushort* h1   = xlr + (size_t)N_NODES * 2 * D1;       // N*512 bf16
    ushort* ylr  = h1 + (size_t)N_NODES * D1;            // N*128 bf16
    int* cnt     = (int*)(ylr + (size_t)N_NODES * 2 * NCLS);
    int* pscan   = cnt + N_NODES;                        // N
    int* bsum    = pscan + N_NODES;                      // 128
    int* row_ptr = bsum + 128;                           // N+1
    int* cursor  = row_ptr + N_NODES + 1;                // N
    int* csr_src = cursor + N_NODES;                     // E

    hipMemsetAsync(cnt, 0, N_NODES * sizeof(int), stream);
    preprocess<<<PB_TOTAL, 256, 0, stream>>>(x, xbf, Wl1, Wr1, Wl2, Wr2, wt1, wt2, dstv, cnt);
    scan_local<<<SCAN_BLOCKS, 256, 0, stream>>>(cnt, pscan, bsum, N_NODES);
    scan_finalize<<<SCAN_BLOCKS, 256, 0, stream>>>(cnt, pscan, bsum, row_ptr, cursor, N_NODES);
    gemm1_scatter<<<G1_BLOCKS + SC_BLOCKS, 256, 0, stream>>>(
        xbf, wt1, xlr, srcv, dstv, cursor, csr_src);
    attn_l1_fused<<<N_NODES, 128, 0, stream>>>(xlr, att1, b1, row_ptr, csr_src, h1);
    gemm2_32x128<<<N_NODES / 32, 256, 0, stream>>>(h1, wt2, ylr);
    attn_l2_fused<<<N_NODES / 4, 256, 0, stream>>>(ylr, att2, b2, row_ptr, csr_src, out);
}

// Round 16
// 215.226 us; speedup vs baseline: 1.0780x; 1.0780x over previous
//
#include <hip/hip_runtime.h>
#include <hip/hip_bf16.h>

#define N_NODES 20000
#define N_EDGES 320000
#define F_IN 256
#define HID 64
#define HEADS 8
#define NCLS 64
#define D1 (HEADS * HID)   // 512
#define SCAN_BLOCKS ((N_NODES + 255) / 256)   // 79

typedef __attribute__((ext_vector_type(8))) short short8;
typedef __attribute__((ext_vector_type(4))) float floatx4;
typedef __attribute__((ext_vector_type(2))) float v2f;

__device__ __forceinline__ ushort f2bf(float f) {
    unsigned u = __float_as_uint(f);
    unsigned r = (u + 0x7fffu + ((u >> 16) & 1u)) >> 16;
    return (ushort)r;
}
__device__ __forceinline__ v2f unpack2(unsigned u) {
    v2f r;
    r.x = __uint_as_float(u << 16);
    r.y = __uint_as_float(u & 0xffff0000u);
    return r;
}
template <int CTRL>
__device__ __forceinline__ float dppadd(float x) {
    int y = __builtin_amdgcn_update_dpp(0, __float_as_int(x), CTRL, 0xF, 0xF, true);
    return x + __int_as_float(y);
}
__device__ __forceinline__ float rowsum16(float x) {
    x = dppadd<0xB1>(x);     // quad_perm [1,0,3,2]
    x = dppadd<0x4E>(x);     // quad_perm [2,3,0,1]
    x = dppadd<0x124>(x);    // row_ror:4
    x = dppadd<0x128>(x);    // row_ror:8
    return x;
}
// async global->LDS 16B per lane (wave-level): LDS dest = uniform base + lane*16
__device__ __forceinline__ void async_copy16(ushort* lds, const ushort* g) {
    __builtin_amdgcn_global_load_lds(
        (const __attribute__((address_space(1))) void*)g,
        (__attribute__((address_space(3))) void*)lds, 16, 0, 0);
}

// ---------- fused preprocess: x->bf16, 4 weight transposes (coalesced reads), histogram ----------
#define PB_HIST 1250
#define PB_CONV 5000
#define PB_T1   512
#define PB_T2   128
#define PB_TOTAL (PB_HIST + PB_CONV + 2 * PB_T1 + 2 * PB_T2)  // 7530
__global__ __launch_bounds__(256) void preprocess(
    const float* __restrict__ x, ushort* __restrict__ xbf,
    const float* __restrict__ Wl1, const float* __restrict__ Wr1,
    const float* __restrict__ Wl2, const float* __restrict__ Wr2,
    ushort* __restrict__ wt1, ushort* __restrict__ wt2,
    const int* __restrict__ dst, int* __restrict__ cnt) {
    int b = blockIdx.x, t = threadIdx.x;
    if (b < PB_HIST) {
        int i = b * 256 + t;
        if (i < N_EDGES) atomicAdd(&cnt[dst[i]], 1);
    } else if (b < PB_HIST + PB_CONV) {
        int i = (b - PB_HIST) * 256 + t;   // float4 index
        if (i < N_NODES * F_IN / 4) {
            float4 v = ((const float4*)x)[i];
            ushort4 o;
            o.x = f2bf(v.x); o.y = f2bf(v.y); o.z = f2bf(v.z); o.w = f2bf(v.w);
            ((ushort4*)xbf)[i] = o;
        }
    } else if (b < PB_HIST + PB_CONV + 2 * PB_T1) {
        int lb = b - PB_HIST - PB_CONV;
        const float* W = (lb < PB_T1) ? Wl1 : Wr1;
        ushort* Wt = wt1 + ((lb < PB_T1) ? 0 : D1 * F_IN);
        int i = (lb % PB_T1) * 256 + t;    // linear over W[k][n], k<256, n<512: coalesced read
        if (i < D1 * F_IN) {
            Wt[(i & 511) * 256 + (i >> 9)] = f2bf(W[i]);
        }
    } else {
        int lb = b - PB_HIST - PB_CONV - 2 * PB_T1;
        const float* W = (lb < PB_T2) ? Wl2 : Wr2;
        ushort* Wt = wt2 + ((lb < PB_T2) ? 0 : NCLS * D1);
        int i = (lb % PB_T2) * 256 + t;    // linear over W[k][n], k<512, n<64: coalesced read
        if (i < NCLS * D1) {
            Wt[(i & 63) * 512 + (i >> 6)] = f2bf(W[i]);
        }
    }
}

// ---------- CSR scan (parallel 2-kernel) ----------
__global__ __launch_bounds__(256) void scan_local(const int* __restrict__ cnt,
                                                  int* __restrict__ pscan,
                                                  int* __restrict__ bsum, int n) {
    int tid = threadIdx.x;
    int i = blockIdx.x * 256 + tid;
    int lane = tid & 63, wave = tid >> 6;
    int v = (i < n) ? cnt[i] : 0;
    int x = v;
    #pragma unroll
    for (int d = 1; d < 64; d <<= 1) {
        int y = __shfl_up(x, d);
        if (lane >= d) x += y;
    }
    __shared__ int wsum[4];
    if (lane == 63) wsum[wave] = x;
    __syncthreads();
    int woff = 0;
    for (int w2 = 0; w2 < wave; w2++) woff += wsum[w2];
    int incl = x + woff;
    if (i < n) pscan[i] = incl;
    if (tid == 255) bsum[blockIdx.x] = incl;
}

__global__ __launch_bounds__(256) void scan_finalize(const int* __restrict__ cnt,
                                                     const int* __restrict__ pscan,
                                                     const int* __restrict__ bsum,
                                                     int* __restrict__ row_ptr,
                                                     int* __restrict__ cursor, int n) {
    int t = threadIdx.x;
    int lane = t & 63, wave = t >> 6;
    int v = (t < SCAN_BLOCKS && t < blockIdx.x) ? bsum[t] : 0;
    #pragma unroll
    for (int mask = 1; mask < 64; mask <<= 1) v += __shfl_xor(v, mask);
    __shared__ int ws[4];
    __shared__ int soff;
    if (lane == 0) ws[wave] = v;
    __syncthreads();
    if (t == 0) soff = ws[0] + ws[1] + ws[2] + ws[3];
    __syncthreads();
    int i = blockIdx.x * 256 + t;
    if (i < n) {
        int incl = pscan[i] + soff;
        row_ptr[i + 1] = incl;
        cursor[i] = incl - cnt[i];
    }
    if (i == 0) row_ptr[0] = 0;
}

// ---------- fused gemm1 (128x128 bf16 MFMA, async LDS staging, row-major BK=32) + scatter ----------
#define G1_NT 8
#define G1_MT ((N_NODES + 127) / 128) // 157
#define G1_BLOCKS (G1_NT * G1_MT)     // 1256
#define SC_BLOCKS (N_EDGES / 256)     // 1250
__global__ __launch_bounds__(256) void gemm1_scatter(
    const ushort* __restrict__ A, const ushort* __restrict__ Bt,
    ushort* __restrict__ C,
    const int* __restrict__ src, const int* __restrict__ dst,
    int* __restrict__ cursor, int* __restrict__ csr_src) {
    if (blockIdx.x >= G1_BLOCKS) {
        int i = (blockIdx.x - G1_BLOCKS) * 256 + threadIdx.x;
        if (i < N_EDGES) {
            int d = dst[i];
            int pos = atomicAdd(&cursor[d], 1);
            csr_src[pos] = src[i];
        }
        return;
    }
    const int M = N_NODES, N = 2 * D1, K = F_IN;
    __shared__ ushort As[128 * 32];
    __shared__ ushort Bs[128 * 32];
    int tid = threadIdx.x;
    int rowBase = (blockIdx.x >> 3) * 128, colBase = (blockIdx.x & 7) * 128;
    int wave = tid >> 6, lane = tid & 63;
    int quad = lane >> 4, m16 = lane & 15;
    int rh = wave >> 1, chf = wave & 1;
    floatx4 acc[4][4];
    #pragma unroll
    for (int i = 0; i < 4; i++)
        #pragma unroll
        for (int j = 0; j < 4; j++) acc[i][j] = (floatx4){0.f, 0.f, 0.f, 0.f};

    for (int k0 = 0; k0 < K; k0 += 32) {
        #pragma unroll
        for (int i = 0; i < 2; i++) {
            int idx = i * 256 + tid;
            int r = idx >> 2, kq = (idx & 3) * 8;
            int grow = min(rowBase + r, M - 1);           // clamp OOB rows (discarded later)
            async_copy16(&As[idx * 8], A + (size_t)grow * K + k0 + kq);
            async_copy16(&Bs[idx * 8], Bt + (size_t)(colBase + r) * K + k0 + kq);
        }
        __syncthreads();
        short8 af[4], bfr[4];
        #pragma unroll
        for (int i = 0; i < 4; i++)
            af[i] = *(short8*)&As[(rh * 64 + i * 16 + m16) * 32 + quad * 8];
        #pragma unroll
        for (int j = 0; j < 4; j++)
            bfr[j] = *(short8*)&Bs[(chf * 64 + j * 16 + m16) * 32 + quad * 8];
        #pragma unroll
        for (int i = 0; i < 4; i++)
            #pragma unroll
            for (int j = 0; j < 4; j++)
                acc[i][j] = __builtin_amdgcn_mfma_f32_16x16x32_bf16(af[i], bfr[j], acc[i][j], 0, 0, 0);
        __syncthreads();
    }
    #pragma unroll
    for (int i = 0; i < 4; i++)
        #pragma unroll
        for (int j = 0; j < 4; j++)
            #pragma unroll
            for (int r = 0; r < 4; r++) {
                int row = rowBase + rh * 64 + i * 16 + quad * 4 + r;
                if (row < M) C[(size_t)row * N + colBase + chf * 64 + j * 16 + m16] = f2bf(acc[i][j][r]);
            }
}

// ---------- gemm2: 32x128 tile, async LDS staging, row-major BK=32 (625 blocks) ----------
__global__ __launch_bounds__(256) void gemm2_32x128(
    const ushort* __restrict__ A, const ushort* __restrict__ Bt,
    ushort* __restrict__ C) {
    const int K = D1;            // 512
    __shared__ ushort As[32 * 32];
    __shared__ ushort Bs[128 * 32];
    int tid = threadIdx.x;
    int rowBase = blockIdx.x * 32;
    int wave = tid >> 6, lane = tid & 63;
    int quad = lane >> 4, m16 = lane & 15;
    floatx4 acc[2][2];
    #pragma unroll
    for (int i = 0; i < 2; i++)
        #pragma unroll
        for (int j = 0; j < 2; j++) acc[i][j] = (floatx4){0.f, 0.f, 0.f, 0.f};

    for (int k0 = 0; k0 < K; k0 += 32) {
        if (tid < 128) {                            // waves 0,1: A tile (128 chunks)
            int r = tid >> 2, kq = (tid & 3) * 8;
            async_copy16(&As[tid * 8], A + (size_t)(rowBase + r) * K + k0 + kq);
        }
        #pragma unroll
        for (int i = 0; i < 2; i++) {               // all waves: B tile (512 chunks)
            int idx = i * 256 + tid;
            int r = idx >> 2, kq = (idx & 3) * 8;
            async_copy16(&Bs[idx * 8], Bt + (size_t)r * K + k0 + kq);
        }
        __syncthreads();
        short8 af[2], bfr[2];
        #pragma unroll
        for (int i = 0; i < 2; i++)
            af[i] = *(short8*)&As[(i * 16 + m16) * 32 + quad * 8];
        #pragma unroll
        for (int j = 0; j < 2; j++)
            bfr[j] = *(short8*)&Bs[(wave * 32 + j * 16 + m16) * 32 + quad * 8];
        #pragma unroll
        for (int i = 0; i < 2; i++)
            #pragma unroll
            for (int j = 0; j < 2; j++)
                acc[i][j] = __builtin_amdgcn_mfma_f32_16x16x32_bf16(af[i], bfr[j], acc[i][j], 0, 0, 0);
        __syncthreads();
    }
    #pragma unroll
    for (int i = 0; i < 2; i++)
        #pragma unroll
        for (int j = 0; j < 2; j++)
            #pragma unroll
            for (int r = 0; r < 4; r++) {
                int row = rowBase + i * 16 + quad * 4 + r;
                C[(size_t)row * 128 + wave * 32 + j * 16 + m16] = f2bf(acc[i][j][r]);
            }
}

// ---------- layer-1 fused attention: R12-measured layout (54.8 us) ----------
// 128 thr/block = 2 waves, ONE node; thread t owns channels 4t..4t+3
// (16-lane head groups -> rowsum16 DPP); depth-4 named prefetch; exp2 prescale.
#define L1PROC(cu, valid)                                                     \
    {                                                                         \
        v2f _c01 = unpack2((cu).x), _c23 = unpack2((cu).y);                   \
        v2f _v01 = _c01 + xr01, _v23 = _c23 + xr23;                           \
        v2f _sp = a6_01 * _v01 + a4_01 * __builtin_elementwise_abs(_v01)      \
                + a6_23 * _v23 + a4_23 * __builtin_elementwise_abs(_v23);     \
        float _sc = _sp.x + _sp.y;                                            \
        _sc = rowsum16(_sc);                                                  \
        float _e = (valid) ? exp2f(_sc) : 0.f;                                \
        den += _e;                                                            \
        v2f _ev = {_e, _e};                                                   \
        ac01 = ac01 + _ev * _c01; ac23 = ac23 + _ev * _c23;                   \
    }

__global__ __launch_bounds__(128) void attn_l1_fused(
    const ushort* __restrict__ xlr, const float* __restrict__ att,
    const float* __restrict__ b1,
    const int* __restrict__ row_ptr, const int* __restrict__ csr_src,
    ushort* __restrict__ h1out) {
    int d = blockIdx.x, t = threadIdx.x;
    int start = row_ptr[d], deg = row_ptr[d + 1] - start;

    uint2 xru = *(const uint2*)(xlr + (size_t)d * 1024 + 512 + 4 * t);
    v2f xr01 = unpack2(xru.x), xr23 = unpack2(xru.y);
    const float C6 = 0.6f * 1.44269504f, C4 = 0.4f * 1.44269504f;
    float4 atv = *(const float4*)(att + 4 * t);
    v2f a6_01 = {C6 * atv.x, C6 * atv.y}, a4_01 = {C4 * atv.x, C4 * atv.y};
    v2f a6_23 = {C6 * atv.z, C6 * atv.w}, a4_23 = {C4 * atv.z, C4 * atv.w};

    float den = 0.f;
    v2f ac01 = {0.f, 0.f}, ac23 = {0.f, 0.f};

    if (deg > 0) {
        const int* cs = csr_src + start;
        uint2 q0 = *(const uint2*)(xlr + (size_t)cs[0] * 1024 + 4 * t);
        uint2 q1 = *(const uint2*)(xlr + (size_t)cs[min(1, deg - 1)] * 1024 + 4 * t);
        uint2 q2 = *(const uint2*)(xlr + (size_t)cs[min(2, deg - 1)] * 1024 + 4 * t);
        uint2 q3 = *(const uint2*)(xlr + (size_t)cs[min(3, deg - 1)] * 1024 + 4 * t);
        for (int i0 = 0; i0 < deg; i0 += 4) {
            uint2 e0 = q0, e1 = q1, e2 = q2, e3 = q3;
            if (i0 + 4 < deg) q0 = *(const uint2*)(xlr + (size_t)cs[i0 + 4] * 1024 + 4 * t);
            if (i0 + 5 < deg) q1 = *(const uint2*)(xlr + (size_t)cs[i0 + 5] * 1024 + 4 * t);
            if (i0 + 6 < deg) q2 = *(const uint2*)(xlr + (size_t)cs[i0 + 6] * 1024 + 4 * t);
            if (i0 + 7 < deg) q3 = *(const uint2*)(xlr + (size_t)cs[i0 + 7] * 1024 + 4 * t);
            L1PROC(e0, true)
            L1PROC(e1, i0 + 1 < deg)
            L1PROC(e2, i0 + 2 < deg)
            L1PROC(e3, i0 + 3 < deg)
        }
    }
    float inv = 1.f / (den + 1e-16f);
    float4 bv = *(const float4*)(b1 + 4 * t);
    float o0 = ac01.x * inv + bv.x;
    float o1 = ac01.y * inv + bv.y;
    float o2 = ac23.x * inv + bv.z;
    float o3 = ac23.y * inv + bv.w;
    o0 = o0 > 0.f ? o0 : (__expf(o0) - 1.f);   // ELU
    o1 = o1 > 0.f ? o1 : (__expf(o1) - 1.f);
    o2 = o2 > 0.f ? o2 : (__expf(o2) - 1.f);
    o3 = o3 > 0.f ? o3 : (__expf(o3) - 1.f);
    ushort4 hv;
    hv.x = f2bf(o0); hv.y = f2bf(o1); hv.z = f2bf(o2); hv.w = f2bf(o3);
    *(ushort4*)(h1out + (size_t)d * D1 + 4 * t) = hv;
}

// ---------- layer-2 fused attention: 16-lane groups, 4 edges/wave/step ----------
#define L2PROC(cu, valid)                                                     \
    {                                                                         \
        v2f _c01 = unpack2((cu).x), _c23 = unpack2((cu).y);                   \
        v2f _v01 = _c01 + yr01, _v23 = _c23 + yr23;                           \
        v2f _sp = at6_01 * _v01 + at4_01 * __builtin_elementwise_abs(_v01)    \
                + at6_23 * _v23 + at4_23 * __builtin_elementwise_abs(_v23);   \
        float _sc = _sp.x + _sp.y;                                            \
        _sc = rowsum16(_sc);                                                  \
        float _e = (valid) ? exp2f(_sc) : 0.f;                                \
        den += _e;                                                            \
        v2f _ev = {_e, _e};                                                   \
        ac01 = ac01 + _ev * _c01; ac23 = ac23 + _ev * _c23;                   \
    }

__device__ __forceinline__ float xgroup_sum(float x) {
    float t = __int_as_float(__builtin_amdgcn_ds_swizzle(__float_as_int(x), 0x401F));
    x += t;
    x += __shfl_xor(x, 32);
    return x;
}

__global__ __launch_bounds__(256) void attn_l2_fused(
    const ushort* __restrict__ ylr, const float* __restrict__ att2,
    const float* __restrict__ b2,
    const int* __restrict__ row_ptr, const int* __restrict__ csr_src,
    float* __restrict__ out) {
    int wave = threadIdx.x >> 6, lane = threadIdx.x & 63;
    int d = blockIdx.x * 4 + wave;
    int grp = lane >> 4, l15 = lane & 15;
    int start = row_ptr[d], deg = row_ptr[d + 1] - start;

    uint2 yru = *(const uint2*)(ylr + (size_t)d * 128 + 64 + 4 * l15);
    v2f yr01 = unpack2(yru.x), yr23 = unpack2(yru.y);
    float4 a2 = *(const float4*)(att2 + 4 * l15);
    const float C6 = 0.6f * 1.44269504f, C4 = 0.4f * 1.44269504f;
    v2f at6_01 = {C6 * a2.x, C6 * a2.y}, at4_01 = {C4 * a2.x, C4 * a2.y};
    v2f at6_23 = {C6 * a2.z, C6 * a2.w}, at4_23 = {C4 * a2.z, C4 * a2.w};

    float den = 0.f;
    v2f ac01 = {0.f, 0.f}, ac23 = {0.f, 0.f};

    if (deg > 0) {
        int S = (deg + 3) >> 2;                 // steps of 4 edges
        const int* cs = csr_src + start;
        uint2 q0 = *(const uint2*)(ylr + (size_t)cs[min(grp, deg - 1)] * 128 + 4 * l15);
        uint2 q1 = *(const uint2*)(ylr + (size_t)cs[min(min(1, S - 1) * 4 + grp, deg - 1)] * 128 + 4 * l15);
        for (int i = 0; i < S; i++) {
            uint2 cu = q0;
            q0 = q1;
            if (i + 2 < S) {
                int p = min((i + 2) * 4 + grp, deg - 1);
                q1 = *(const uint2*)(ylr + (size_t)cs[p] * 128 + 4 * l15);
            }
            L2PROC(cu, 4 * i + grp < deg)
        }
        den = xgroup_sum(den);
        ac01.x = xgroup_sum(ac01.x);
        ac01.y = xgroup_sum(ac01.y);
        ac23.x = xgroup_sum(ac23.x);
        ac23.y = xgroup_sum(ac23.y);
    }
    if (grp == 0) {
        float inv = 1.f / (den + 1e-16f);
        float4 bv = *(const float4*)(b2 + 4 * l15);
        float4 o;
        o.x = ac01.x * inv + bv.x;
        o.y = ac01.y * inv + bv.y;
        o.z = ac23.x * inv + bv.z;
        o.w = ac23.y * inv + bv.w;
        *(float4*)(out + (size_t)d * NCLS + 4 * l15) = o;
    }
}

extern "C" void kernel_launch(void* const* d_in, const int* in_sizes, int n_in,
                              void* d_out, int out_size, void* d_ws, size_t ws_size,
                              hipStream_t stream) {
    const float* x    = (const float*)d_in[0];
    const int*   edge = (const int*)d_in[1];
    const float* Wl1  = (const float*)d_in[2];
    const float* Wr1  = (const float*)d_in[3];
    const float* att1 = (const float*)d_in[4];
    const float* b1   = (const float*)d_in[5];
    const float* Wl2  = (const float*)d_in[6];
    const float* Wr2  = (const float*)d_in[7];
    const float* att2 = (const float*)d_in[8];
    const float* b2   = (const float*)d_in[9];
    float* out = (float*)d_out;

    const int* srcv = edge;
    const int* dstv = edge + N_EDGES;

    ushort* xbf  = (ushort*)d_ws;                        // N*256
    ushort* wt1  = xbf + (size_t)N_NODES * F_IN;         // 1024*256 (Wl1^T || Wr1^T)
    ushort* wt2  = wt1 + 2 * D1 * F_IN;                  // 128*512  (Wl2^T || Wr2^T)
    ushort* xlr  = wt2 + 2 * NCLS * D1;                  // N*1024 bf16
    ushort* h1   = xlr + (size_t)N_NODES * 2 * D1;       // N*512 bf16
    ushort* ylr  = h1 + (size_t)N_NODES * D1;            // N*128 bf16
    int* cnt     = (int*)(ylr + (size_t)N_NODES * 2 * NCLS);
    int* pscan   = cnt + N_NODES;                        // N
    int* bsum    = pscan + N_NODES;                      // 128
    int* row_ptr = bsum + 128;                           // N+1
    int* cursor  = row_ptr + N_NODES + 1;                // N
    int* csr_src = cursor + N_NODES;                     // E

    hipMemsetAsync(cnt, 0, N_NODES * sizeof(int), stream);
    preprocess<<<PB_TOTAL, 256, 0, stream>>>(x, xbf, Wl1, Wr1, Wl2, Wr2, wt1, wt2, dstv, cnt);
    scan_local<<<SCAN_BLOCKS, 256, 0, stream>>>(cnt, pscan, bsum, N_NODES);
    scan_finalize<<<SCAN_BLOCKS, 256, 0, stream>>>(cnt, pscan, bsum, row_ptr, cursor, N_NODES);
    gemm1_scatter<<<G1_BLOCKS + SC_BLOCKS, 256, 0, stream>>>(
        xbf, wt1, xlr, srcv, dstv, cursor, csr_src);
    attn_l1_fused<<<N_NODES, 128, 0, stream>>>(xlr, att1, b1, row_ptr, csr_src, h1);
    gemm2_32x128<<<N_NODES / 32, 256, 0, stream>>>(h1, wt2, ylr);
    attn_l2_fused<<<N_NODES / 4, 256, 0, stream>>>(ylr, att2, b2, row_ptr, csr_src, out);
}